// Round 19
// baseline (821.844 us; speedup 1.0000x reference)
//
#include <hip/hip_runtime.h>

#define N_PTS  4096
#define N_CENT 1024
#define K_S    32
#define EPSV   1e-5f

typedef __attribute__((ext_vector_type(8))) short short8;
typedef __attribute__((ext_vector_type(4))) float floatx4;
typedef __attribute__((ext_vector_type(2))) float float2v;

__device__ inline unsigned short bf1(float x) {
  unsigned u = __float_as_uint(x);
  u += 0x7fffu + ((u >> 16) & 1u);
  return (unsigned short)(u >> 16);
}
__device__ inline unsigned pkbf(float a, float b) {
  return (unsigned)bf1(a) | ((unsigned)bf1(b) << 16);
}

// Agent-scope atomics operate at the LLC on gfx950 (sc1).
// R14: never ACQUIRE-spin (per-poll L1+L2 invalidate -> 12-53ms).
// R17/R18: never __threadfence() in the producer loop (buffer_wbl2 writeback,
// ~23us total). Protocol: data stores = RELAXED agent atomics (complete at
// LLC); __syncthreads() drains vmcnt per-wave before s_barrier -> after the
// barrier data is LLC-visible; flag store (relaxed agent) follows.
__device__ inline unsigned aload_rlx(const unsigned* p) {
  return __hip_atomic_load(p, __ATOMIC_RELAXED, __HIP_MEMORY_SCOPE_AGENT);
}
__device__ inline void astore_rlx(unsigned* p, unsigned v) {
  __hip_atomic_store(p, v, __ATOMIC_RELAXED, __HIP_MEMORY_SCOPE_AGENT);
}
__device__ inline float aload_f(const float* p) {
  unsigned v = __hip_atomic_load((const unsigned*)p, __ATOMIC_RELAXED,
                                 __HIP_MEMORY_SCOPE_AGENT);
  return __uint_as_float(v);
}
__device__ inline void astore_f(float* p, float v) {
  __hip_atomic_store((unsigned*)p, __float_as_uint(v), __ATOMIC_RELAXED,
                     __HIP_MEMORY_SCOPE_AGENT);
}

// ws byte layout:
//   0     : WB0 bf16 [64 o][96 k]   12288: WB1 [64][64]   20480: WB2 [128][64]
//   36864 : Bf0 f32[64]  37120: Bf1 f32[64]  37376: Bf2 f32[128]
//   38400 : cnt u32, one per 64B line x 16 batches (zeroed by prep each run)
//   65536 : nidx int[16*1024*32]  (2 MB)
__global__ void prep_kernel(const float* __restrict__ W0, const float* __restrict__ b0,
                            const float* __restrict__ g0, const float* __restrict__ be0,
                            const float* __restrict__ m0, const float* __restrict__ v0,
                            const float* __restrict__ W1, const float* __restrict__ b1,
                            const float* __restrict__ g1, const float* __restrict__ be1,
                            const float* __restrict__ m1, const float* __restrict__ v1,
                            const float* __restrict__ W2, const float* __restrict__ b2,
                            const float* __restrict__ g2, const float* __restrict__ be2,
                            const float* __restrict__ m2, const float* __restrict__ v2,
                            unsigned char* __restrict__ wsb) {
  const int stride = gridDim.x * blockDim.x;
  const int tid = blockIdx.x * blockDim.x + threadIdx.x;
  unsigned short* WB0 = (unsigned short*)wsb;
  unsigned short* WB1 = (unsigned short*)(wsb + 12288);
  unsigned short* WB2 = (unsigned short*)(wsb + 20480);
  float* Bf0 = (float*)(wsb + 36864);
  float* Bf1 = (float*)(wsb + 37120);
  float* Bf2 = (float*)(wsb + 37376);
  unsigned* cntz = (unsigned*)(wsb + 38400);
  for (int i = tid; i < 16; i += stride) cntz[i * 16] = 0u;  // 64B-strided lines
  for (int i = tid; i < 64 * 96; i += stride) {
    int o = i / 96, k = i - o * 96;
    float s = g0[o] * rsqrtf(v0[o] + EPSV);
    float val = 0.0f;
    if (k < 64) val = W0[o * 67 + 3 + k] * s;
    else if (k < 67) val = W0[o * 67 + (k - 64)] * s;
    WB0[i] = bf1(val);
  }
  for (int i = tid; i < 64; i += stride) {
    float s = g0[i] * rsqrtf(v0[i] + EPSV);
    Bf0[i] = (b0[i] - m0[i]) * s + be0[i];
  }
  for (int i = tid; i < 64 * 64; i += stride) {
    int o = i >> 6;
    float s = g1[o] * rsqrtf(v1[o] + EPSV);
    WB1[i] = bf1(W1[i] * s);
  }
  for (int i = tid; i < 64; i += stride) {
    float s = g1[i] * rsqrtf(v1[i] + EPSV);
    Bf1[i] = (b1[i] - m1[i]) * s + be1[i];
  }
  for (int i = tid; i < 128 * 64; i += stride) {
    int o = i >> 6;
    float s = g2[o] * rsqrtf(v2[o] + EPSV);
    WB2[i] = bf1(W2[i] * s);
  }
  for (int i = tid; i < 128; i += stride) {
    float s = g2[i] * rsqrtf(v2[i] + EPSV);
    Bf2[i] = (b2[i] - m2[i]) * s + be2[i];
  }
}

// LDS union: fps view (50.8KB) / worker view (53.2KB) / pad to 84KB so
// 2x86016 > 163840 -> exactly 1 block/CU (exclusive CU, dispatch-order-safe).
struct FpsS {
  float lx[N_PTS], ly[N_PTS], lz[N_PTS];
  float stage[2 * 192];
  unsigned long long rkey[2 * 4];
};
union SmemU {
  FpsS f;
  unsigned short h[256 * 104];
  unsigned char pad[86016];
};

#define DPP_STEP(CTRL)                                                               \
  {                                                                                  \
    unsigned lo2 = (unsigned)__builtin_amdgcn_update_dpp(                            \
        0, (int)(unsigned)key, (CTRL), 0xf, 0xf, false);                             \
    unsigned hi2 = (unsigned)__builtin_amdgcn_update_dpp(                            \
        0, (int)(unsigned)(key >> 32), (CTRL), 0xf, 0xf, false);                     \
    unsigned long long nk = ((unsigned long long)hi2 << 32) | lo2;                   \
    if (nk > key) key = nk;                                                          \
  }

// ---- FPS producer in its own __noinline__ function: private regalloc +
// compact contiguous code for the hot 1023-iter loop (R19 theory: sharing
// codegen with the unrolled MFMA worker path cost ~60us vs R11's standalone
// fps kernel; VGPR 192 vs 88 and scattered layout).
__device__ __attribute__((noinline)) void fps_produce(
    const float* __restrict__ xyz, unsigned* cnt, float* new_xyz, FpsS* S) {
#pragma clang fp contract(off)
  const int b = blockIdx.x;
  const int tid = threadIdx.x;
  const int lane = tid & 63, wv = tid >> 6;
  const float* X = xyz + (size_t)b * N_PTS * 3;
  float* outc = new_xyz + (size_t)b * N_CENT * 3;
  float* lx = S->lx;
  float* ly = S->ly;
  float* lz = S->lz;
  float* stage = S->stage;
  unsigned long long* rkey = S->rkey;
  float2v px[8], py[8], pz[8], dist[8];
#pragma unroll
  for (int j = 0; j < 16; ++j) {
    int p = j * 256 + tid;
    float x = X[p * 3 + 0], y = X[p * 3 + 1], z = X[p * 3 + 2];
    lx[p] = x; ly[p] = y; lz[p] = z;
    int t = j >> 1;
    if ((j & 1) == 0) { px[t].x = x; py[t].x = y; pz[t].x = z; dist[t].x = 1e10f; }
    else              { px[t].y = x; py[t].y = y; pz[t].y = z; dist[t].y = 1e10f; }
  }
  __syncthreads();
  int far = 0;
  for (int i = 1; i < N_CENT; ++i) {
    const int c = i - 1;  // centroid finalized this iteration
    float cx = lx[far], cy = ly[far], cz = lz[far];
    // stage centroid c from registers (off critical chain)
    if (wv == 0 && lane < 3) {
      float cv = lane == 0 ? cx : (lane == 1 ? cy : cz);
      stage[((c >> 6) & 1) * 192 + (c & 63) * 3 + lane] = cv;
    }
    const bool pub = (c >= 64) && ((c & 63) == 0);
    const int q = (c >> 6) - 1;  // chunk to publish (buffer q&1, != (c>>6)&1)
    // sc1 atomic stores: complete at LLC, no dirty L2, no fence needed.
    if (pub && tid < 192) astore_f(&outc[q * 192 + tid], stage[(q & 1) * 192 + tid]);
    float2v cx2 = {cx, cx}, cy2 = {cy, cy}, cz2 = {cz, cz};
    float best = -1.0f;
    int bi = 0;
#pragma unroll
    for (int t = 0; t < 8; ++t) {
      float2v dx = px[t] - cx2, dy = py[t] - cy2, dz = pz[t] - cz2;
      float2v d2 = dx * dx + dy * dy + dz * dz;  // pk math, contract off
      float d0 = fminf(dist[t].x, d2.x); dist[t].x = d0;
      if (d0 > best) { best = d0; bi = (2 * t) * 256 + tid; }
      float d1 = fminf(dist[t].y, d2.y); dist[t].y = d1;
      if (d1 > best) { best = d1; bi = (2 * t + 1) * 256 + tid; }
    }
    unsigned long long key =
        ((unsigned long long)__float_as_uint(best) << 32) | (unsigned)(~bi);
    DPP_STEP(0x111);  // row_shr:1
    DPP_STEP(0x112);  // row_shr:2
    DPP_STEP(0x114);  // row_shr:4
    DPP_STEP(0x118);  // row_shr:8
    DPP_STEP(0x142);  // row_bcast15
    DPP_STEP(0x143);  // row_bcast31 -> lane 63 has wave winner
    const int par = i & 1;
    if (lane == 63) rkey[par * 4 + wv] = key;
    // __syncthreads drains each wave's vmcnt before s_barrier -> after it,
    // this iteration's sc1 data stores are LLC-visible; flag follows.
    __syncthreads();
    unsigned long long k0 = rkey[par * 4 + 0], k1 = rkey[par * 4 + 1];
    unsigned long long k2 = rkey[par * 4 + 2], k3 = rkey[par * 4 + 3];
    if (k1 > k0) k0 = k1;
    if (k3 > k2) k2 = k3;
    if (k2 > k0) k0 = k2;
    far = (int)~(unsigned)k0;
    if (pub && tid == 0) astore_rlx(cnt + b * 16, (unsigned)((q + 1) * 64));
  }
  // final centroid 1023 from the final far
  if (tid < 3) {
    const float* arr = tid == 0 ? lx : (tid == 1 ? ly : lz);
    stage[1 * 192 + 63 * 3 + tid] = arr[far];  // (1023>>6)&1 == 1, slot 63
  }
  __syncthreads();
  // publish remaining chunk 15 (entries 960..1023, buffer 1), sc1 stores
  if (tid < 192) astore_f(&outc[15 * 192 + tid], stage[1 * 192 + tid]);
  __syncthreads();  // drains vmcnt -> chunk-15 data LLC-visible
  if (tid == 0) astore_rlx(cnt + b * 16, (unsigned)N_CENT);
}

// ---- persistent worker in its own __noinline__ function ----
__device__ __attribute__((noinline)) void worker_run(
    const float* __restrict__ xyz, const float* __restrict__ points,
    const unsigned char* __restrict__ wsb, unsigned* cnt, int* nid_g,
    float* new_xyz, float* __restrict__ out_pts, unsigned short* h) {
#pragma clang fp contract(off)
  const int tid = threadIdx.x;
  const int lane = tid & 63, wv = tid >> 6;
  const int w2 = (int)blockIdx.x - 16;  // 0..239
  // chunk = s0idx*16 + b: increasing chunk id == increasing s0 -> workers
  // always take the earliest-ready work; per-worker waits are monotone.
  for (int chunk = w2; chunk < 2048; chunk += 240) {
    const int b = chunk & 15;
    const int s0 = (chunk >> 4) << 3;
    const unsigned need = (unsigned)(s0 + 8);
    // RELAXED sleep-spin: no cache maintenance per poll.
    while (aload_rlx(cnt + b * 16) < need) __builtin_amdgcn_s_sleep(32);

    const float* Xb = xyz + (size_t)b * N_PTS * 3;
    // ---- ball query (decisions bit-identical; centroid reads LLC-atomic) ----
    {
      const float r2 = (float)(0.2 * 0.2);
      const int sA = s0 + wv * 2, sB = sA + 1;
      float cxA = aload_f(&new_xyz[((size_t)b * N_CENT + sA) * 3 + 0]);
      float cyA = aload_f(&new_xyz[((size_t)b * N_CENT + sA) * 3 + 1]);
      float czA = aload_f(&new_xyz[((size_t)b * N_CENT + sA) * 3 + 2]);
      float cxB = aload_f(&new_xyz[((size_t)b * N_CENT + sB) * 3 + 0]);
      float cyB = aload_f(&new_xyz[((size_t)b * N_CENT + sB) * 3 + 1]);
      float czB = aload_f(&new_xyz[((size_t)b * N_CENT + sB) * 3 + 2]);
      float scA = cxA * cxA + cyA * cyA + czA * czA;
      float scB = cxB * cxB + cyB * cyB + czB * czB;
      int* outA = nid_g + ((size_t)b * N_CENT + sA) * K_S;
      int* outB = nid_g + ((size_t)b * N_CENT + sB) * K_S;
      int cntA = 0, cntB = 0, firstA = 0, firstB = 0;
      for (int base = 0; base < N_PTS && (cntA < K_S || cntB < K_S); base += 64) {
        int p = base + lane;
        float x = Xb[p * 3 + 0], y = Xb[p * 3 + 1], z = Xb[p * 3 + 2];
        float sp = x * x + y * y + z * z;
        float dtA = __builtin_fmaf(czA, z, __builtin_fmaf(cyA, y, cxA * x));
        float dtB = __builtin_fmaf(czB, z, __builtin_fmaf(cyB, y, cxB * x));
        float d2A = (scA + sp) - 2.0f * dtA;
        float d2B = (scB + sp) - 2.0f * dtB;
        bool inA = !(d2A > r2);
        bool inB = !(d2B > r2);
        unsigned long long mA = __ballot(inA);
        unsigned long long mB = __ballot(inB);
        if (cntA == 0 && mA != 0ull) firstA = base + __builtin_ctzll(mA);
        if (cntB == 0 && mB != 0ull) firstB = base + __builtin_ctzll(mB);
        unsigned long long below = (1ull << lane) - 1ull;
        int posA = cntA + __popcll(mA & below);
        int posB = cntB + __popcll(mB & below);
        if (inA && posA < K_S) outA[posA] = p;
        if (inB && posB < K_S) outB[posB] = p;
        cntA += __popcll(mA);
        cntB += __popcll(mB);
      }
      if (cntA < K_S)
        for (int j = cntA + lane; j < K_S; j += 64) outA[j] = firstA;
      if (cntB < K_S)
        for (int j = cntB + lane; j < K_S; j += 64) outB[j] = firstB;
    }
    // barrier: (a) each wave's nid_g writes drained before its own reads,
    // (b) all waves done reading h (prev chunk layer-3) before gather rewrites
    __syncthreads();

    // ---- gather + 3-layer bf16-MFMA MLP + maxpool ----
    {
      const int s = s0 + (tid >> 5);
      const int id = nid_g[((size_t)b * N_CENT + s0) * K_S + tid];  // own-wave rows
      float cx = aload_f(&new_xyz[((size_t)b * N_CENT + s) * 3 + 0]);
      float cy = aload_f(&new_xyz[((size_t)b * N_CENT + s) * 3 + 1]);
      float cz = aload_f(&new_xyz[((size_t)b * N_CENT + s) * 3 + 2]);
      float gx = Xb[id * 3 + 0] - cx;
      float gy = Xb[id * 3 + 1] - cy;
      float gz = Xb[id * 3 + 2] - cz;
      unsigned short* hrow = &h[tid * 104];
      const float4* P = (const float4*)(points + ((size_t)b * N_PTS + id) * 64);
#pragma unroll
      for (int c8 = 0; c8 < 8; ++c8) {
        float4 u = P[2 * c8], v = P[2 * c8 + 1];
        uint4 w4;
        w4.x = pkbf(u.x, u.y); w4.y = pkbf(u.z, u.w);
        w4.z = pkbf(v.x, v.y); w4.w = pkbf(v.z, v.w);
        *(uint4*)(hrow + c8 * 8) = w4;
      }
      uint4 t4;
      t4.x = pkbf(gx, gy); t4.y = pkbf(gz, 0.0f); t4.z = 0u; t4.w = 0u;
      *(uint4*)(hrow + 64) = t4;
      uint4 z4; z4.x = z4.y = z4.z = z4.w = 0u;
      *(uint4*)(hrow + 72) = z4;
      *(uint4*)(hrow + 80) = z4;
      *(uint4*)(hrow + 88) = z4;
    }
    __syncthreads();

    const int col = lane & 15, kq = lane >> 4;
    const int w = wv;
    const unsigned short* WB0 = (const unsigned short*)wsb;
    const unsigned short* WB1 = (const unsigned short*)(wsb + 12288);
    const unsigned short* WB2 = (const unsigned short*)(wsb + 20480);
    const float* Bf0 = (const float*)(wsb + 36864);
    const float* Bf1 = (const float*)(wsb + 37120);
    const float* Bf2 = (const float*)(wsb + 37376);

    // ---- layer 1: K=96 (3 chunks), N=64 ----
    {
      const int o = w * 16 + col;
      float bias = Bf0[o];
      floatx4 acc[16];
#pragma unroll
      for (int mt = 0; mt < 16; ++mt) acc[mt] = floatx4{bias, bias, bias, bias};
#pragma unroll
      for (int c = 0; c < 3; ++c) {
        short8 bf = *(const short8*)(WB0 + o * 96 + kq * 8 + 32 * c);
#pragma unroll
        for (int mt = 0; mt < 16; ++mt) {
          short8 af = *(const short8*)(&h[(mt * 16 + col) * 104 + kq * 8 + 32 * c]);
          acc[mt] = __builtin_amdgcn_mfma_f32_16x16x32_bf16(af, bf, acc[mt], 0, 0, 0);
        }
      }
      __syncthreads();
#pragma unroll
      for (int mt = 0; mt < 16; ++mt)
#pragma unroll
        for (int r = 0; r < 4; ++r)
          h[(mt * 16 + kq * 4 + r) * 104 + o] = bf1(fmaxf(acc[mt][r], 0.0f));
      __syncthreads();
    }

    // ---- layer 2: K=64 (2 chunks), N=64 ----
    {
      const int o = w * 16 + col;
      float bias = Bf1[o];
      floatx4 acc[16];
#pragma unroll
      for (int mt = 0; mt < 16; ++mt) acc[mt] = floatx4{bias, bias, bias, bias};
#pragma unroll
      for (int c = 0; c < 2; ++c) {
        short8 bf = *(const short8*)(WB1 + o * 64 + kq * 8 + 32 * c);
#pragma unroll
        for (int mt = 0; mt < 16; ++mt) {
          short8 af = *(const short8*)(&h[(mt * 16 + col) * 104 + kq * 8 + 32 * c]);
          acc[mt] = __builtin_amdgcn_mfma_f32_16x16x32_bf16(af, bf, acc[mt], 0, 0, 0);
        }
      }
      __syncthreads();
#pragma unroll
      for (int mt = 0; mt < 16; ++mt)
#pragma unroll
        for (int r = 0; r < 4; ++r)
          h[(mt * 16 + kq * 4 + r) * 104 + o] = bf1(fmaxf(acc[mt][r], 0.0f));
      __syncthreads();
    }

    // ---- layer 3: K=64, N=128 + maxpool ----
    {
      const int oA = w * 32 + col;
      const int oB = oA + 16;
      float biasA = Bf2[oA], biasB = Bf2[oB];
      floatx4 accA[16], accB[16];
#pragma unroll
      for (int mt = 0; mt < 16; ++mt) {
        accA[mt] = floatx4{biasA, biasA, biasA, biasA};
        accB[mt] = floatx4{biasB, biasB, biasB, biasB};
      }
#pragma unroll
      for (int c = 0; c < 2; ++c) {
        short8 bfA = *(const short8*)(WB2 + oA * 64 + kq * 8 + 32 * c);
        short8 bfB = *(const short8*)(WB2 + oB * 64 + kq * 8 + 32 * c);
#pragma unroll
        for (int mt = 0; mt < 16; ++mt) {
          short8 af = *(const short8*)(&h[(mt * 16 + col) * 104 + kq * 8 + 32 * c]);
          accA[mt] = __builtin_amdgcn_mfma_f32_16x16x32_bf16(af, bfA, accA[mt], 0, 0, 0);
          accB[mt] = __builtin_amdgcn_mfma_f32_16x16x32_bf16(af, bfB, accB[mt], 0, 0, 0);
        }
      }
#pragma unroll
      for (int mtp = 0; mtp < 8; ++mtp) {
        float vA = fmaxf(fmaxf(fmaxf(accA[2 * mtp][0], accA[2 * mtp + 1][0]),
                               fmaxf(accA[2 * mtp][1], accA[2 * mtp + 1][1])),
                         fmaxf(fmaxf(accA[2 * mtp][2], accA[2 * mtp + 1][2]),
                               fmaxf(accA[2 * mtp][3], accA[2 * mtp + 1][3])));
        float vB = fmaxf(fmaxf(fmaxf(accB[2 * mtp][0], accB[2 * mtp + 1][0]),
                               fmaxf(accB[2 * mtp][1], accB[2 * mtp + 1][1])),
                         fmaxf(fmaxf(accB[2 * mtp][2], accB[2 * mtp + 1][2]),
                               fmaxf(accB[2 * mtp][3], accB[2 * mtp + 1][3])));
        vA = fmaxf(vA, __shfl_xor(vA, 16)); vA = fmaxf(vA, __shfl_xor(vA, 32));
        vB = fmaxf(vB, __shfl_xor(vB, 16)); vB = fmaxf(vB, __shfl_xor(vB, 32));
        vA = fmaxf(vA, 0.0f); vB = fmaxf(vB, 0.0f);
        if (lane < 16) {
          float* op = out_pts + ((size_t)(b * N_CENT + s0 + mtp)) * 128;
          op[oA] = vA;
          op[oB] = vB;
        }
      }
    }
  }
}

// ---- fused, EXCLUSIVE-CU persistent grid: 256 blocks = 16 fps + 240 workers
__launch_bounds__(256)
__global__ void fused_kernel(const float* __restrict__ xyz,
                             const float* __restrict__ points,
                             const unsigned char* __restrict__ wsb,
                             unsigned* cnt,
                             int* nid_g,
                             float* new_xyz,
                             float* __restrict__ out_pts) {
  __shared__ __align__(16) SmemU u;  // 84KB -> 1 block/CU
  if (blockIdx.x < 16) {
    fps_produce(xyz, cnt, new_xyz, &u.f);
  } else {
    worker_run(xyz, points, wsb, cnt, nid_g, new_xyz, out_pts, u.h);
  }
}

extern "C" void kernel_launch(void* const* d_in, const int* in_sizes, int n_in,
                              void* d_out, int out_size, void* d_ws, size_t ws_size,
                              hipStream_t stream) {
  const float* xyz = (const float*)d_in[0];
  const float* points = (const float*)d_in[1];
  float* out = (float*)d_out;
  float* new_xyz = out;                  // (16,1024,3)
  float* out_pts = out + 16 * 1024 * 3;  // (16,1024,128)
  unsigned char* wsb = (unsigned char*)d_ws;
  unsigned* cnt = (unsigned*)(wsb + 38400);
  int* nid_g = (int*)(wsb + 65536);

  prep_kernel<<<64, 256, 0, stream>>>(
      (const float*)d_in[2], (const float*)d_in[3], (const float*)d_in[4],
      (const float*)d_in[5], (const float*)d_in[6], (const float*)d_in[7],
      (const float*)d_in[8], (const float*)d_in[9], (const float*)d_in[10],
      (const float*)d_in[11], (const float*)d_in[12], (const float*)d_in[13],
      (const float*)d_in[14], (const float*)d_in[15], (const float*)d_in[16],
      (const float*)d_in[17], (const float*)d_in[18], (const float*)d_in[19], wsb);
  // grid 256 == capacity at 1 block/CU (84KB LDS union): every block has a
  // private CU from t=0. 16 fps producers + 240 persistent workers.
  fused_kernel<<<256, 256, 0, stream>>>(xyz, points, wsb, cnt, nid_g,
                                        new_xyz, out_pts);
}

// Round 21
// 766.174 us; speedup vs baseline: 1.0727x; 1.0727x over previous
//
#include <hip/hip_runtime.h>

#define N_PTS  4096
#define N_CENT 1024
#define K_S    32
#define EPSV   1e-5f

typedef __attribute__((ext_vector_type(8))) short short8;
typedef __attribute__((ext_vector_type(4))) float floatx4;
typedef __attribute__((ext_vector_type(2))) float float2v;

__device__ inline unsigned short bf1(float x) {
  unsigned u = __float_as_uint(x);
  u += 0x7fffu + ((u >> 16) & 1u);
  return (unsigned short)(u >> 16);
}
__device__ inline unsigned pkbf(float a, float b) {
  return (unsigned)bf1(a) | ((unsigned)bf1(b) << 16);
}

// Agent-scope atomics operate at the LLC on gfx950 (sc1): loads read LLC,
// stores complete at LLC (no dirty private-L2 line).
// R14 lesson: never ACQUIRE-spin (L1+L2 invalidate per poll -> 12-53ms).
// R17/R18 lesson: never __threadfence() in the producer loop (buffer_wbl2
// writes back ALL dirty XCD L2 lines; removing it was -23us).
// R19 lesson: do NOT split paths into __noinline__ functions (ABI forces
// VGPR 192->220, FETCH/WRITE 3x, +55us). Single inlined kernel is optimal.
// Publication protocol: data stores = RELAXED agent atomics (complete at
// LLC); __syncthreads() drains vmcnt per-wave before s_barrier (compiler-
// guaranteed), so after the barrier all data is LLC-visible; flag store =
// RELAXED agent atomic issued after the barrier -> ordered behind the data.
__device__ inline unsigned aload_rlx(const unsigned* p) {
  return __hip_atomic_load(p, __ATOMIC_RELAXED, __HIP_MEMORY_SCOPE_AGENT);
}
__device__ inline void astore_rlx(unsigned* p, unsigned v) {
  __hip_atomic_store(p, v, __ATOMIC_RELAXED, __HIP_MEMORY_SCOPE_AGENT);
}
__device__ inline float aload_f(const float* p) {
  unsigned v = __hip_atomic_load((const unsigned*)p, __ATOMIC_RELAXED,
                                 __HIP_MEMORY_SCOPE_AGENT);
  return __uint_as_float(v);
}
__device__ inline void astore_f(float* p, float v) {
  __hip_atomic_store((unsigned*)p, __float_as_uint(v), __ATOMIC_RELAXED,
                     __HIP_MEMORY_SCOPE_AGENT);
}

// ws byte layout:
//   0     : WB0 bf16 [64 o][96 k]   12288: WB1 [64][64]   20480: WB2 [128][64]
//   36864 : Bf0 f32[64]  37120: Bf1 f32[64]  37376: Bf2 f32[128]
//   38400 : cnt u32, one per 64B line x 16 batches (zeroed by prep each run)
//   65536 : nidx int[16*1024*32]  (2 MB)
__global__ void prep_kernel(const float* __restrict__ W0, const float* __restrict__ b0,
                            const float* __restrict__ g0, const float* __restrict__ be0,
                            const float* __restrict__ m0, const float* __restrict__ v0,
                            const float* __restrict__ W1, const float* __restrict__ b1,
                            const float* __restrict__ g1, const float* __restrict__ be1,
                            const float* __restrict__ m1, const float* __restrict__ v1,
                            const float* __restrict__ W2, const float* __restrict__ b2,
                            const float* __restrict__ g2, const float* __restrict__ be2,
                            const float* __restrict__ m2, const float* __restrict__ v2,
                            unsigned char* __restrict__ wsb) {
  const int stride = gridDim.x * blockDim.x;
  const int tid = blockIdx.x * blockDim.x + threadIdx.x;
  unsigned short* WB0 = (unsigned short*)wsb;
  unsigned short* WB1 = (unsigned short*)(wsb + 12288);
  unsigned short* WB2 = (unsigned short*)(wsb + 20480);
  float* Bf0 = (float*)(wsb + 36864);
  float* Bf1 = (float*)(wsb + 37120);
  float* Bf2 = (float*)(wsb + 37376);
  unsigned* cntz = (unsigned*)(wsb + 38400);
  for (int i = tid; i < 16; i += stride) cntz[i * 16] = 0u;  // 64B-strided lines
  for (int i = tid; i < 64 * 96; i += stride) {
    int o = i / 96, k = i - o * 96;
    float s = g0[o] * rsqrtf(v0[o] + EPSV);
    float val = 0.0f;
    if (k < 64) val = W0[o * 67 + 3 + k] * s;
    else if (k < 67) val = W0[o * 67 + (k - 64)] * s;
    WB0[i] = bf1(val);
  }
  for (int i = tid; i < 64; i += stride) {
    float s = g0[i] * rsqrtf(v0[i] + EPSV);
    Bf0[i] = (b0[i] - m0[i]) * s + be0[i];
  }
  for (int i = tid; i < 64 * 64; i += stride) {
    int o = i >> 6;
    float s = g1[o] * rsqrtf(v1[o] + EPSV);
    WB1[i] = bf1(W1[i] * s);
  }
  for (int i = tid; i < 64; i += stride) {
    float s = g1[i] * rsqrtf(v1[i] + EPSV);
    Bf1[i] = (b1[i] - m1[i]) * s + be1[i];
  }
  for (int i = tid; i < 128 * 64; i += stride) {
    int o = i >> 6;
    float s = g2[o] * rsqrtf(v2[o] + EPSV);
    WB2[i] = bf1(W2[i] * s);
  }
  for (int i = tid; i < 128; i += stride) {
    float s = g2[i] * rsqrtf(v2[i] + EPSV);
    Bf2[i] = (b2[i] - m2[i]) * s + be2[i];
  }
}

// ---- fused, EXCLUSIVE-CU persistent grid: 256 blocks = 16 fps + 240 workers
// Static LDS 86016B -> 1 block/CU; grid 256 == capacity -> every block owns a
// CU from t=0 (dispatch-order-safe). R16/R17 A/B: worker count (240 vs 64)
// is ~neutral -> workers are not the constraint; the ~90us fused-fps
// inflation tracked to the per-publication __threadfence (wbl2) -> removed
// (see publication protocol above). fps = R11 core + 64-granular publication.
// Outputs bit-identical to R11.
#define DPP_STEP(CTRL)                                                               \
  {                                                                                  \
    unsigned lo2 = (unsigned)__builtin_amdgcn_update_dpp(                            \
        0, (int)(unsigned)key, (CTRL), 0xf, 0xf, false);                             \
    unsigned hi2 = (unsigned)__builtin_amdgcn_update_dpp(                            \
        0, (int)(unsigned)(key >> 32), (CTRL), 0xf, 0xf, false);                     \
    unsigned long long nk = ((unsigned long long)hi2 << 32) | lo2;                   \
    if (nk > key) key = nk;                                                          \
  }

__launch_bounds__(256)
__global__ void fused_kernel(const float* __restrict__ xyz,
                             const float* __restrict__ points,
                             const unsigned char* __restrict__ wsb,
                             unsigned* cnt,
                             int* nid_g,
                             float* new_xyz,
                             float* __restrict__ out_pts) {
#pragma clang fp contract(off)
  // static 84KB pad -> 1 block/CU on gfx950 (160KB LDS/CU)
  __shared__ __align__(16) unsigned char smem[86016];
  const int tid = threadIdx.x;
  const int lane = tid & 63, wv = tid >> 6;

  if (blockIdx.x < 16) {
    // ================= FPS producer (exclusive CU) =================
    const int b = blockIdx.x;
    const float* X = xyz + (size_t)b * N_PTS * 3;
    float* outc = new_xyz + (size_t)b * N_CENT * 3;
    float* lx = (float*)smem;                 // [4096]
    float* ly = lx + N_PTS;                   // [4096]
    float* lz = ly + N_PTS;                   // [4096]
    float* stage = lz + N_PTS;                // [2][192]
    unsigned long long* rkey = (unsigned long long*)(stage + 384);  // [2][4]
    float2v px[8], py[8], pz[8], dist[8];
#pragma unroll
    for (int j = 0; j < 16; ++j) {
      int p = j * 256 + tid;
      float x = X[p * 3 + 0], y = X[p * 3 + 1], z = X[p * 3 + 2];
      lx[p] = x; ly[p] = y; lz[p] = z;
      int t = j >> 1;
      if ((j & 1) == 0) { px[t].x = x; py[t].x = y; pz[t].x = z; dist[t].x = 1e10f; }
      else              { px[t].y = x; py[t].y = y; pz[t].y = z; dist[t].y = 1e10f; }
    }
    __syncthreads();
    int far = 0;
    for (int i = 1; i < N_CENT; ++i) {
      const int c = i - 1;  // centroid finalized this iteration
      float cx = lx[far], cy = ly[far], cz = lz[far];
      // stage centroid c from registers (off critical chain)
      if (wv == 0 && lane < 3) {
        float cv = lane == 0 ? cx : (lane == 1 ? cy : cz);
        stage[((c >> 6) & 1) * 192 + (c & 63) * 3 + lane] = cv;
      }
      const bool pub = (c >= 64) && ((c & 63) == 0);
      const int q = (c >> 6) - 1;  // chunk to publish (buffer q&1, != (c>>6)&1)
      // sc1 atomic stores: complete at LLC, no dirty L2, no fence needed.
      if (pub && tid < 192) astore_f(&outc[q * 192 + tid], stage[(q & 1) * 192 + tid]);
      float2v cx2 = {cx, cx}, cy2 = {cy, cy}, cz2 = {cz, cz};
      float best = -1.0f;
      int bi = 0;
#pragma unroll
      for (int t = 0; t < 8; ++t) {
        float2v dx = px[t] - cx2, dy = py[t] - cy2, dz = pz[t] - cz2;
        float2v d2 = dx * dx + dy * dy + dz * dz;  // pk math, contract off
        float d0 = fminf(dist[t].x, d2.x); dist[t].x = d0;
        if (d0 > best) { best = d0; bi = (2 * t) * 256 + tid; }
        float d1 = fminf(dist[t].y, d2.y); dist[t].y = d1;
        if (d1 > best) { best = d1; bi = (2 * t + 1) * 256 + tid; }
      }
      unsigned long long key =
          ((unsigned long long)__float_as_uint(best) << 32) | (unsigned)(~bi);
      DPP_STEP(0x111);  // row_shr:1
      DPP_STEP(0x112);  // row_shr:2
      DPP_STEP(0x114);  // row_shr:4
      DPP_STEP(0x118);  // row_shr:8
      DPP_STEP(0x142);  // row_bcast15
      DPP_STEP(0x143);  // row_bcast31 -> lane 63 has wave winner
      const int par = i & 1;
      if (lane == 63) rkey[par * 4 + wv] = key;
      // __syncthreads drains each wave's vmcnt before s_barrier (compiler-
      // guaranteed) -> after it, this iteration's sc1 data stores are
      // LLC-visible; the flag store below is therefore ordered behind them.
      __syncthreads();
      unsigned long long k0 = rkey[par * 4 + 0], k1 = rkey[par * 4 + 1];
      unsigned long long k2 = rkey[par * 4 + 2], k3 = rkey[par * 4 + 3];
      if (k1 > k0) k0 = k1;
      if (k3 > k2) k2 = k3;
      if (k2 > k0) k0 = k2;
      far = (int)~(unsigned)k0;
      if (pub && tid == 0) astore_rlx(cnt + b * 16, (unsigned)((q + 1) * 64));
    }
    // final centroid 1023 from the final far
    if (tid < 3) {
      const float* arr = tid == 0 ? lx : (tid == 1 ? ly : lz);
      stage[1 * 192 + 63 * 3 + tid] = arr[far];  // (1023>>6)&1 == 1, slot 63
    }
    __syncthreads();
    // publish remaining chunk 15 (entries 960..1023, buffer 1), sc1 stores
    if (tid < 192) astore_f(&outc[15 * 192 + tid], stage[1 * 192 + tid]);
    __syncthreads();  // drains vmcnt -> chunk-15 data LLC-visible
    if (tid == 0) astore_rlx(cnt + b * 16, (unsigned)N_CENT);
    return;
  }

  // ============ persistent worker: 240 blocks over 2048 chunks ============
  // chunk = s0idx*16 + b: increasing chunk id == increasing s0 -> workers
  // always take the earliest-ready work; per-worker waits are monotone.
  unsigned short* h = (unsigned short*)smem;  // [256*104]
  const int w2 = (int)blockIdx.x - 16;        // 0..239
  for (int chunk = w2; chunk < 2048; chunk += 240) {
    const int b = chunk & 15;
    const int s0 = (chunk >> 4) << 3;
    const unsigned need = (unsigned)(s0 + 8);
    // RELAXED sleep-spin (see notes): no cache maintenance per poll.
    while (aload_rlx(cnt + b * 16) < need) __builtin_amdgcn_s_sleep(32);

    const float* Xb = xyz + (size_t)b * N_PTS * 3;
    // ---- ball query (decisions bit-identical; centroid reads LLC-atomic) ----
    {
      const float r2 = (float)(0.2 * 0.2);
      const int sA = s0 + wv * 2, sB = sA + 1;
      float cxA = aload_f(&new_xyz[((size_t)b * N_CENT + sA) * 3 + 0]);
      float cyA = aload_f(&new_xyz[((size_t)b * N_CENT + sA) * 3 + 1]);
      float czA = aload_f(&new_xyz[((size_t)b * N_CENT + sA) * 3 + 2]);
      float cxB = aload_f(&new_xyz[((size_t)b * N_CENT + sB) * 3 + 0]);
      float cyB = aload_f(&new_xyz[((size_t)b * N_CENT + sB) * 3 + 1]);
      float czB = aload_f(&new_xyz[((size_t)b * N_CENT + sB) * 3 + 2]);
      float scA = cxA * cxA + cyA * cyA + czA * czA;
      float scB = cxB * cxB + cyB * cyB + czB * czB;
      int* outA = nid_g + ((size_t)b * N_CENT + sA) * K_S;
      int* outB = nid_g + ((size_t)b * N_CENT + sB) * K_S;
      int cntA = 0, cntB = 0, firstA = 0, firstB = 0;
      for (int base = 0; base < N_PTS && (cntA < K_S || cntB < K_S); base += 64) {
        int p = base + lane;
        float x = Xb[p * 3 + 0], y = Xb[p * 3 + 1], z = Xb[p * 3 + 2];
        float sp = x * x + y * y + z * z;
        float dtA = __builtin_fmaf(czA, z, __builtin_fmaf(cyA, y, cxA * x));
        float dtB = __builtin_fmaf(czB, z, __builtin_fmaf(cyB, y, cxB * x));
        float d2A = (scA + sp) - 2.0f * dtA;
        float d2B = (scB + sp) - 2.0f * dtB;
        bool inA = !(d2A > r2);
        bool inB = !(d2B > r2);
        unsigned long long mA = __ballot(inA);
        unsigned long long mB = __ballot(inB);
        if (cntA == 0 && mA != 0ull) firstA = base + __builtin_ctzll(mA);
        if (cntB == 0 && mB != 0ull) firstB = base + __builtin_ctzll(mB);
        unsigned long long below = (1ull << lane) - 1ull;
        int posA = cntA + __popcll(mA & below);
        int posB = cntB + __popcll(mB & below);
        if (inA && posA < K_S) outA[posA] = p;
        if (inB && posB < K_S) outB[posB] = p;
        cntA += __popcll(mA);
        cntB += __popcll(mB);
      }
      if (cntA < K_S)
        for (int j = cntA + lane; j < K_S; j += 64) outA[j] = firstA;
      if (cntB < K_S)
        for (int j = cntB + lane; j < K_S; j += 64) outB[j] = firstB;
    }
    // barrier: (a) each wave's nid_g writes drained before its own reads,
    // (b) all waves done reading h (prev chunk layer-3) before gather rewrites
    __syncthreads();

    // ---- gather + 3-layer bf16-MFMA MLP + maxpool ----
    {
      const int s = s0 + (tid >> 5);
      const int id = nid_g[((size_t)b * N_CENT + s0) * K_S + tid];  // own-wave rows
      float cx = aload_f(&new_xyz[((size_t)b * N_CENT + s) * 3 + 0]);
      float cy = aload_f(&new_xyz[((size_t)b * N_CENT + s) * 3 + 1]);
      float cz = aload_f(&new_xyz[((size_t)b * N_CENT + s) * 3 + 2]);
      float gx = Xb[id * 3 + 0] - cx;
      float gy = Xb[id * 3 + 1] - cy;
      float gz = Xb[id * 3 + 2] - cz;
      unsigned short* hrow = &h[tid * 104];
      const float4* P = (const float4*)(points + ((size_t)b * N_PTS + id) * 64);
#pragma unroll
      for (int c8 = 0; c8 < 8; ++c8) {
        float4 u = P[2 * c8], v = P[2 * c8 + 1];
        uint4 w4;
        w4.x = pkbf(u.x, u.y); w4.y = pkbf(u.z, u.w);
        w4.z = pkbf(v.x, v.y); w4.w = pkbf(v.z, v.w);
        *(uint4*)(hrow + c8 * 8) = w4;
      }
      uint4 t4;
      t4.x = pkbf(gx, gy); t4.y = pkbf(gz, 0.0f); t4.z = 0u; t4.w = 0u;
      *(uint4*)(hrow + 64) = t4;
      uint4 z4; z4.x = z4.y = z4.z = z4.w = 0u;
      *(uint4*)(hrow + 72) = z4;
      *(uint4*)(hrow + 80) = z4;
      *(uint4*)(hrow + 88) = z4;
    }
    __syncthreads();

    const int col = lane & 15, kq = lane >> 4;
    const int w = wv;
    const unsigned short* WB0 = (const unsigned short*)wsb;
    const unsigned short* WB1 = (const unsigned short*)(wsb + 12288);
    const unsigned short* WB2 = (const unsigned short*)(wsb + 20480);
    const float* Bf0 = (const float*)(wsb + 36864);
    const float* Bf1 = (const float*)(wsb + 37120);
    const float* Bf2 = (const float*)(wsb + 37376);

    // ---- layer 1: K=96 (3 chunks), N=64 ----
    {
      const int o = w * 16 + col;
      float bias = Bf0[o];
      floatx4 acc[16];
#pragma unroll
      for (int mt = 0; mt < 16; ++mt) acc[mt] = floatx4{bias, bias, bias, bias};
#pragma unroll
      for (int c = 0; c < 3; ++c) {
        short8 bf = *(const short8*)(WB0 + o * 96 + kq * 8 + 32 * c);
#pragma unroll
        for (int mt = 0; mt < 16; ++mt) {
          short8 af = *(const short8*)(&h[(mt * 16 + col) * 104 + kq * 8 + 32 * c]);
          acc[mt] = __builtin_amdgcn_mfma_f32_16x16x32_bf16(af, bf, acc[mt], 0, 0, 0);
        }
      }
      __syncthreads();
#pragma unroll
      for (int mt = 0; mt < 16; ++mt)
#pragma unroll
        for (int r = 0; r < 4; ++r)
          h[(mt * 16 + kq * 4 + r) * 104 + o] = bf1(fmaxf(acc[mt][r], 0.0f));
      __syncthreads();
    }

    // ---- layer 2: K=64 (2 chunks), N=64 ----
    {
      const int o = w * 16 + col;
      float bias = Bf1[o];
      floatx4 acc[16];
#pragma unroll
      for (int mt = 0; mt < 16; ++mt) acc[mt] = floatx4{bias, bias, bias, bias};
#pragma unroll
      for (int c = 0; c < 2; ++c) {
        short8 bf = *(const short8*)(WB1 + o * 64 + kq * 8 + 32 * c);
#pragma unroll
        for (int mt = 0; mt < 16; ++mt) {
          short8 af = *(const short8*)(&h[(mt * 16 + col) * 104 + kq * 8 + 32 * c]);
          acc[mt] = __builtin_amdgcn_mfma_f32_16x16x32_bf16(af, bf, acc[mt], 0, 0, 0);
        }
      }
      __syncthreads();
#pragma unroll
      for (int mt = 0; mt < 16; ++mt)
#pragma unroll
        for (int r = 0; r < 4; ++r)
          h[(mt * 16 + kq * 4 + r) * 104 + o] = bf1(fmaxf(acc[mt][r], 0.0f));
      __syncthreads();
    }

    // ---- layer 3: K=64, N=128 + maxpool ----
    {
      const int oA = w * 32 + col;
      const int oB = oA + 16;
      float biasA = Bf2[oA], biasB = Bf2[oB];
      floatx4 accA[16], accB[16];
#pragma unroll
      for (int mt = 0; mt < 16; ++mt) {
        accA[mt] = floatx4{biasA, biasA, biasA, biasA};
        accB[mt] = floatx4{biasB, biasB, biasB, biasB};
      }
#pragma unroll
      for (int c = 0; c < 2; ++c) {
        short8 bfA = *(const short8*)(WB2 + oA * 64 + kq * 8 + 32 * c);
        short8 bfB = *(const short8*)(WB2 + oB * 64 + kq * 8 + 32 * c);
#pragma unroll
        for (int mt = 0; mt < 16; ++mt) {
          short8 af = *(const short8*)(&h[(mt * 16 + col) * 104 + kq * 8 + 32 * c]);
          accA[mt] = __builtin_amdgcn_mfma_f32_16x16x32_bf16(af, bfA, accA[mt], 0, 0, 0);
          accB[mt] = __builtin_amdgcn_mfma_f32_16x16x32_bf16(af, bfB, accB[mt], 0, 0, 0);
        }
      }
#pragma unroll
      for (int mtp = 0; mtp < 8; ++mtp) {
        float vA = fmaxf(fmaxf(fmaxf(accA[2 * mtp][0], accA[2 * mtp + 1][0]),
                               fmaxf(accA[2 * mtp][1], accA[2 * mtp + 1][1])),
                         fmaxf(fmaxf(accA[2 * mtp][2], accA[2 * mtp + 1][2]),
                               fmaxf(accA[2 * mtp][3], accA[2 * mtp + 1][3])));
        float vB = fmaxf(fmaxf(fmaxf(accB[2 * mtp][0], accB[2 * mtp + 1][0]),
                               fmaxf(accB[2 * mtp][1], accB[2 * mtp + 1][1])),
                         fmaxf(fmaxf(accB[2 * mtp][2], accB[2 * mtp + 1][2]),
                               fmaxf(accB[2 * mtp][3], accB[2 * mtp + 1][3])));
        vA = fmaxf(vA, __shfl_xor(vA, 16)); vA = fmaxf(vA, __shfl_xor(vA, 32));
        vB = fmaxf(vB, __shfl_xor(vB, 16)); vB = fmaxf(vB, __shfl_xor(vB, 32));
        vA = fmaxf(vA, 0.0f); vB = fmaxf(vB, 0.0f);
        if (lane < 16) {
          float* op = out_pts + ((size_t)(b * N_CENT + s0 + mtp)) * 128;
          op[oA] = vA;
          op[oB] = vB;
        }
      }
    }
  }
}

extern "C" void kernel_launch(void* const* d_in, const int* in_sizes, int n_in,
                              void* d_out, int out_size, void* d_ws, size_t ws_size,
                              hipStream_t stream) {
  const float* xyz = (const float*)d_in[0];
  const float* points = (const float*)d_in[1];
  float* out = (float*)d_out;
  float* new_xyz = out;                  // (16,1024,3)
  float* out_pts = out + 16 * 1024 * 3;  // (16,1024,128)
  unsigned char* wsb = (unsigned char*)d_ws;
  unsigned* cnt = (unsigned*)(wsb + 38400);
  int* nid_g = (int*)(wsb + 65536);

  prep_kernel<<<64, 256, 0, stream>>>(
      (const float*)d_in[2], (const float*)d_in[3], (const float*)d_in[4],
      (const float*)d_in[5], (const float*)d_in[6], (const float*)d_in[7],
      (const float*)d_in[8], (const float*)d_in[9], (const float*)d_in[10],
      (const float*)d_in[11], (const float*)d_in[12], (const float*)d_in[13],
      (const float*)d_in[14], (const float*)d_in[15], (const float*)d_in[16],
      (const float*)d_in[17], (const float*)d_in[18], (const float*)d_in[19], wsb);
  // grid 256 == capacity at 1 block/CU (84KB static LDS pad): every block has
  // a private CU from t=0. 16 fps producers + 240 persistent workers.
  fused_kernel<<<256, 256, 0, stream>>>(xyz, points, wsb, cnt, nid_g,
                                        new_xyz, out_pts);
}